// Round 15
// baseline (101.523 us; speedup 1.0000x reference)
//
#include <hip/hip_runtime.h>
#include <math.h>

#define NCC 80
#define TOPKK 13
#define BB 16
#define NAA 8400
#define NMX 64
#define NROW (BB * NMX)        // 1024
#define NBA  (BB * NAA)        // 134400
#define RCAP 256               // per-row positive capacity (E[n_pos]~4)
#define RPAD 16                // rcount: one counter per 64B line
#define WCAP (NMX * TOPKK)     // 832 winner entries max per batch
#define SENT 0x7fffffff
#define NZ (NROW * RPAD + 16 + NBA)   // rcount | done | w zero region
#define NZ4 (NZ / 4)
#define EPSF 1e-9f
#define IOUEPS 1e-7f
#define INV_PI2 0.4052847345693511f

__device__ __forceinline__ float ciou_pos(float gx1, float gy1, float gx2, float gy2,
                                          float gw, float gh, float gat, float inter,
                                          float px1, float py1, float px2, float py2)
{
    float w2 = px2 - px1, h2 = py2 - py1;
    float uni = gw * gh + w2 * h2 - inter + IOUEPS;
    float iou = inter / uni;
    float cw = fmaxf(gx2, px2) - fminf(gx1, px1);
    float ch = fmaxf(gy2, py2) - fminf(gy1, py1);
    float c2 = cw * cw + ch * ch + IOUEPS;
    float dx = px1 + px2 - gx1 - gx2;
    float dy = py1 + py2 - gy1 - gy2;
    float rho2 = (dx * dx + dy * dy) * 0.25f;
    float da = atanf(w2 / h2) - gat;
    float v = INV_PI2 * da * da;
    float alpha = v / (v - iou + (1.f + IOUEPS));
    return iou - (rho2 / c2 + v * alpha);
}

__device__ __forceinline__ float ciou2(float gx1, float gy1, float gx2, float gy2,
                                       float gw, float gh, float gat,
                                       float px1, float py1, float px2, float py2,
                                       float pat)
{
    float w2 = px2 - px1, h2 = py2 - py1;
    float iw = fmaxf(fminf(gx2, px2) - fmaxf(gx1, px1), 0.f);
    float ih = fmaxf(fminf(gy2, py2) - fmaxf(gy1, py1), 0.f);
    float inter = iw * ih;
    float uni = gw * gh + w2 * h2 - inter + IOUEPS;
    float iou = inter / uni;
    float cw = fmaxf(gx2, px2) - fminf(gx1, px1);
    float ch = fmaxf(gy2, py2) - fminf(gy1, py1);
    float c2 = cw * cw + ch * ch + IOUEPS;
    float dx = px1 + px2 - gx1 - gx2;
    float dy = py1 + py2 - gy1 - gy2;
    float rho2 = (dx * dx + dy * dy) * 0.25f;
    float da = pat - gat;
    float v = INV_PI2 * da * da;
    float alpha = v / (v - iou + (1.f + IOUEPS));
    return iou - (rho2 / c2 + v * alpha);
}

// KZ: zero rcount | done | w (contiguous).
__global__ __launch_bounds__(256) void kz_zero(int4* __restrict__ z)
{
    int i = blockIdx.x * 256 + threadIdx.x;
    if (i < NZ4) z[i] = make_int4(0, 0, 0, 0);
}

// KP: anchor-major positivity scan + last-block-per-batch finalize.
// Scan: one thread per (b,anchor); 64 LDS gt rows; positives (al>0) append
// (al, idx) to per-row lists (ballot-aggregated, padded counters).
// Finalize (last arriving block of the batch, tail-reduction pattern):
//   B: per-row winners (fast path n<=13: positives + ranked din fillers
//      from {0..12}; slow path: exact (val desc, idx asc) wave tournament)
//   C: fg = occurrence count of each winner anchor over the batch
//   D: fg>1 -> is-max row (wave-parallel: 64 lanes = 64 rows, first-argmax)
//   E: recompute (al, ov) w.r.t. the assigned row (din+mask-checked)
//   F: per-row pa/po maxima in LDS -> pos; write w=(tj<<1)|1 and val.
__global__ __launch_bounds__(256) void kp_scan(
    const float* __restrict__ pd_scores,
    const float* __restrict__ pd_bboxes,
    const float* __restrict__ anc,
    const int*   __restrict__ gt_labels,
    const float* __restrict__ gt_bboxes,
    const float* __restrict__ mask_gt,
    int* __restrict__ rcount, int* __restrict__ done,
    int* __restrict__ w, float* __restrict__ val,
    float* __restrict__ rV, int* __restrict__ rI,
    int* __restrict__ pos)
{
    const int tid = threadIdx.x;
    const int lane = tid & 63, wid = tid >> 6;
    const int b = blockIdx.y;
    const int a = blockIdx.x * 256 + tid;
    const bool valid = a < NAA;

    __shared__ float4 glds[NMX];
    __shared__ float  mlds[NMX];
    __shared__ float  galds[NMX];
    __shared__ int    gllds[NMX];
    if (tid < NMX) {
        float4 gg = reinterpret_cast<const float4*>(gt_bboxes)[b * NMX + tid];
        glds[tid] = gg;
        mlds[tid] = mask_gt[b * NMX + tid];
        galds[tid] = atanf((gg.z - gg.x) / (gg.w - gg.y));
        gllds[tid] = gt_labels[b * NMX + tid];
    }
    __syncthreads();

    const float2* ap2 = reinterpret_cast<const float2*>(anc);
    const float4* pb = reinterpret_cast<const float4*>(pd_bboxes) + (size_t)b * NAA;
    float2 ap = valid ? ap2[a] : make_float2(-1e9f, -1e9f);
    float4 p  = valid ? pb[a] : make_float4(0.f, 0.f, 0.f, 0.f);
    const float* scb = pd_scores + ((size_t)b * NAA + a) * NCC;

    for (int j = 0; j < NMX; ++j) {
        float4 g = glds[j];
        float din = fminf(fminf(ap.x - g.x, ap.y - g.y), fminf(g.z - ap.x, g.w - ap.y));
        bool cand = false;
        float al = 0.f;
        if (din > EPSF && mlds[j] > 0.f) {
            float iw = fminf(g.z, p.z) - fmaxf(g.x, p.x);
            float ih = fminf(g.w, p.w) - fmaxf(g.y, p.y);
            if (iw > 0.f && ih > 0.f) {
                float c = ciou_pos(g.x, g.y, g.z, g.w, g.z - g.x, g.w - g.y,
                                   galds[j], iw * ih, p.x, p.y, p.z, p.w);
                float o = fmaxf(c, 0.f);
                float o2 = o * o;
                al = scb[gllds[j]] * (o2 * o2 * o2);
                cand = al > 0.f;
            }
        }
        unsigned long long m = __ballot(cand);
        if (m) {
            const int row = b * NMX + j;
            int base = 0;
            int wc = __popcll(m);
            if (lane == 0) base = atomicAdd(&rcount[row * RPAD], wc);
            base = __shfl(base, 0, 64);
            if (cand) {
                int pp = base + __popcll(m & ((1ull << lane) - 1ull));
                if (pp < RCAP) {
                    rV[(size_t)row * RCAP + pp] = al;
                    rI[(size_t)row * RCAP + pp] = a;
                }
            }
        }
    }

    // ---- tail-reduction handoff: last arriving block of this batch ----
    __shared__ int isLast;
    __threadfence();
    __syncthreads();
    if (tid == 0) {
        int old = __hip_atomic_fetch_add(&done[b], 1, __ATOMIC_ACQ_REL,
                                         __HIP_MEMORY_SCOPE_AGENT);
        isLast = (old == (int)gridDim.x - 1);
    }
    __syncthreads();
    if (!isLast) return;

    // =================== FINALIZE (one block per batch) ===================
    __shared__ int   wAnc[WCAP];
    __shared__ short wRowA[WCAP];
    __shared__ float wAl[WCAP];
    __shared__ short fgE[WCAP];
    __shared__ short tjE[WCAP];
    __shared__ float alE[WCAP];
    __shared__ float ovE[WCAP];
    __shared__ unsigned int paL[NMX], poL[NMX];
    __shared__ int nW;
    if (tid == 0) nW = 0;
    if (tid < NMX) { paL[tid] = 0u; poL[tid] = 0u; }
    __syncthreads();

    // ---- phase B: winner selection, wave wid handles rows wid*16..+15 ----
    for (int rr = 0; rr < 16; ++rr) {
        const int r = wid * 16 + rr;
        if (mlds[r] <= 0.f) continue;
        const int row = b * NMX + r;
        int n = rcount[row * RPAD]; if (n > RCAP) n = RCAP;
        const float4 g = glds[r];

        if (n <= TOPKK) {
            int ai = -1; float ali = 0.f;
            unsigned int pm = 0;
            if (lane < n) {
                ai = rI[(size_t)row * RCAP + lane];
                ali = rV[(size_t)row * RCAP + lane];
                if (ai < TOPKK) pm = 1u << ai;
            }
#pragma unroll
            for (int s = 1; s < 64; s <<= 1) pm |= __shfl_xor(pm, s, 64);
            if (lane < n) {
                int sl = atomicAdd(&nW, 1);
                wAnc[sl] = ai; wRowA[sl] = (short)r; wAl[sl] = ali;
            }
            if (lane < TOPKK) {
                unsigned int bits = (~pm) & 0x1fffu;
                if ((bits >> lane) & 1u) {
                    int rank = __popc(bits & ((1u << lane) - 1u));
                    if (rank < TOPKK - n) {
                        float2 apf = ap2[lane];
                        float din = fminf(fminf(apf.x - g.x, apf.y - g.y),
                                          fminf(g.z - apf.x, g.w - apf.y));
                        if (din > EPSF) {
                            int sl = atomicAdd(&nW, 1);
                            wAnc[sl] = lane; wRowA[sl] = (short)r; wAl[sl] = 0.f;
                        }
                    }
                }
            }
        } else {
            // slow path: exact top-13 (val desc, idx asc) of positives
            float lv[TOPKK]; int li[TOPKK];
#pragma unroll
            for (int k = 0; k < TOPKK; ++k) { lv[k] = -1.f; li[k] = SENT; }
            for (int t = lane; t < n; t += 64) {
                float alx = rV[(size_t)row * RCAP + t];
                int ax = rI[(size_t)row * RCAP + t];
                if (alx > lv[TOPKK - 1] || (alx == lv[TOPKK - 1] && ax < li[TOPKK - 1])) {
                    lv[TOPKK - 1] = alx; li[TOPKK - 1] = ax;
#pragma unroll
                    for (int k = TOPKK - 1; k > 0; --k) {
                        if (lv[k] > lv[k - 1] || (lv[k] == lv[k - 1] && li[k] < li[k - 1])) {
                            float tv = lv[k]; lv[k] = lv[k - 1]; lv[k - 1] = tv;
                            int ti = li[k]; li[k] = li[k - 1]; li[k - 1] = ti;
                        } else break;
                    }
                }
            }
            int pp = 0;
            float myv = -1.f; int myi = SENT;
            for (int rnd = 0; rnd < TOPKK; ++rnd) {
                float hv = -1.f; int hi = SENT;
#pragma unroll
                for (int k = 0; k < TOPKK; ++k) if (pp == k) { hv = lv[k]; hi = li[k]; }
                float wv = hv; int wi = hi;
#pragma unroll
                for (int s = 1; s < 64; s <<= 1) {
                    float ov = __shfl_xor(wv, s, 64);
                    int   oi = __shfl_xor(wi, s, 64);
                    if (ov > wv || (ov == wv && oi < wi)) { wv = ov; wi = oi; }
                }
                if (lane == rnd) { myv = wv; myi = wi; }
                if (hi == wi && wi != SENT) ++pp;
            }
            if (lane < TOPKK && myi != SENT) {
                int sl = atomicAdd(&nW, 1);
                wAnc[sl] = myi; wRowA[sl] = (short)r; wAl[sl] = myv;
            }
        }
    }
    __syncthreads();
    const int nw = nW;

    // ---- phase C: fg = occurrence count ----
    for (int e = tid; e < nw; e += 256) {
        int a0 = wAnc[e];
        int c = 0;
        for (int q = 0; q < nw; ++q) c += (wAnc[q] == a0);
        fgE[e] = (short)c;
    }
    __syncthreads();

    // ---- phase D: assignment (fg>1 -> wave-parallel is-max over 64 rows) ----
    for (int e = wid; e < nw; e += 4) {
        if (fgE[e] <= 1) {
            if (lane == 0) tjE[e] = wRowA[e];
        } else {
            int a0 = wAnc[e];
            float4 pbx = pb[a0];
            float pat = atanf((pbx.z - pbx.x) / (pbx.w - pbx.y));
            float2 apf = ap2[a0];
            int r = lane;                       // 64 lanes = 64 rows
            float4 gr = glds[r];
            float din = fminf(fminf(apf.x - gr.x, apf.y - gr.y),
                              fminf(gr.z - apf.x, gr.w - apf.y));
            float ov = 0.f;
            if (din > EPSF && mlds[r] > 0.f) {
                float c = ciou2(gr.x, gr.y, gr.z, gr.w, gr.z - gr.x, gr.w - gr.y,
                                galds[r], pbx.x, pbx.y, pbx.z, pbx.w, pat);
                ov = fmaxf(c, 0.f);
            }
            float bv = ov; int br = r;
#pragma unroll
            for (int s = 1; s < 64; s <<= 1) {
                float ov2 = __shfl_xor(bv, s, 64);
                int   r2 = __shfl_xor(br, s, 64);
                if (ov2 > bv || (ov2 == bv && r2 < br)) { bv = ov2; br = r2; }
            }
            if (lane == 0) tjE[e] = (short)br;  // first-argmax
        }
    }
    __syncthreads();

    // ---- phase E: (al, ov) w.r.t. assigned row ----
    for (int e = tid; e < nw; e += 256) {
        int tj = tjE[e], a0 = wAnc[e];
        float al2 = 0.f, ov2 = 0.f;
        float2 apf = ap2[a0];
        float4 gr = glds[tj];
        float din = fminf(fminf(apf.x - gr.x, apf.y - gr.y),
                          fminf(gr.z - apf.x, gr.w - apf.y));
        if (din > EPSF && mlds[tj] > 0.f) {
            float4 pbx = pb[a0];
            float pat = atanf((pbx.z - pbx.x) / (pbx.w - pbx.y));
            float c = ciou2(gr.x, gr.y, gr.z, gr.w, gr.z - gr.x, gr.w - gr.y,
                            galds[tj], pbx.x, pbx.y, pbx.z, pbx.w, pat);
            ov2 = fmaxf(c, 0.f);
            float s = pd_scores[((size_t)b * NAA + a0) * NCC + gllds[tj]];
            float o2 = ov2 * ov2;
            al2 = s * (o2 * o2 * o2);
        }
        alE[e] = al2; ovE[e] = ov2;
    }
    __syncthreads();

    // ---- phase F: pa/po maxima + per-anchor assignment writes ----
    for (int e = tid; e < nw; e += 256) {
        int tj = tjE[e], a0 = wAnc[e];
        atomicMax(&paL[tj], __float_as_uint(alE[e]));
        if (ovE[e] > 0.f) atomicMax(&poL[tj], __float_as_uint(ovE[e]));
        w[(size_t)b * NAA + a0] = (tj << 1) | 1;
        val[(size_t)b * NAA + a0] = alE[e];
    }
    __syncthreads();
    if (tid < NMX) {
        pos[b * NMX + tid] = (int)paL[tid];
        pos[NROW + b * NMX + tid] = (int)poL[tid];
    }
}

// K3: all outputs from w/val/pos; score region via coalesced float4 stores.
__global__ __launch_bounds__(256) void k3_out(
    const int* __restrict__ gt_labels,
    const float* __restrict__ gt_bboxes,
    const int* __restrict__ w, const float* __restrict__ val,
    const int* __restrict__ pos,
    float* __restrict__ o_lab, float* __restrict__ o_box, float* __restrict__ o_sc,
    float* __restrict__ o_fg, float* __restrict__ o_ti)
{
    const int id0 = blockIdx.x * 256;
    const int tid = threadIdx.x;
    const int id = id0 + tid;
    const int b = id / NAA;
    const int wv = w[id];
    const int f = wv & 1;
    const int tj = wv >> 1;
    int lab = gt_labels[b * NMX + tj]; lab = lab < 0 ? 0 : lab;
    float4 gb = reinterpret_cast<const float4*>(gt_bboxes)[b * NMX + tj];
    o_lab[id] = (float)lab;
    reinterpret_cast<float4*>(o_box)[id] = gb;
    o_fg[id] = f ? 1.f : 0.f;
    o_ti[id] = (float)tj;
    float v = 0.f;
    if (f) {
        float pa = __uint_as_float((unsigned int)pos[b * NMX + tj]);
        float po = __uint_as_float((unsigned int)pos[NROW + b * NMX + tj]);
        v = (val[id] * po) / (pa + EPSF);
    }
    __shared__ int   s_lab[256];
    __shared__ float s_val[256];
    s_lab[tid] = lab;
    s_val[tid] = v;
    __syncthreads();
    float4* dst = reinterpret_cast<float4*>(o_sc + (size_t)id0 * NCC);
    const int NV = 256 * NCC / 4;   // 5120 float4s per block
#pragma unroll 4
    for (int i = tid; i < NV; i += 256) {
        int aa = i / (NCC / 4);
        int c0 = (i - aa * (NCC / 4)) * 4;
        int la = s_lab[aa];
        float vv = s_val[aa];
        float4 ww;
        ww.x = (la == c0 + 0) ? vv : 0.f;
        ww.y = (la == c0 + 1) ? vv : 0.f;
        ww.z = (la == c0 + 2) ? vv : 0.f;
        ww.w = (la == c0 + 3) ? vv : 0.f;
        dst[i] = ww;
    }
}

extern "C" void kernel_launch(void* const* d_in, const int* in_sizes, int n_in,
                              void* d_out, int out_size, void* d_ws, size_t ws_size,
                              hipStream_t stream)
{
    const float* pd_scores = (const float*)d_in[0];
    const float* pd_bboxes = (const float*)d_in[1];
    const float* anc       = (const float*)d_in[2];
    // d_in[3] rfields: unused by the reference
    const int*   gt_labels = (const int*)d_in[4];
    const float* gt_bboxes = (const float*)d_in[5];
    const float* mask_gt   = (const float*)d_in[6];

    const size_t nba = (size_t)NBA;
    int* rcount = (int*)d_ws;                       // NROW*RPAD
    int* done   = rcount + NROW * RPAD;             // 16
    int* w      = done + 16;                        // NBA
    float* val  = (float*)(w + nba);                // NBA
    float* rV   = val + nba;                        // NROW*RCAP
    int* rI     = (int*)(rV + (size_t)NROW * RCAP); // NROW*RCAP
    int* pos    = rI + (size_t)NROW * RCAP;         // 2*NROW

    float* out = (float*)d_out;
    float* o_lab = out;                 // (B,NA)
    float* o_box = out + nba;           // (B,NA,4)
    float* o_sc  = out + nba * 5;       // (B,NA,NC)
    float* o_fg  = out + nba * 85;      // (B,NA)
    float* o_ti  = out + nba * 86;      // (B,NA)

    kz_zero<<<(NZ4 + 255) / 256, 256, 0, stream>>>((int4*)d_ws);
    kp_scan<<<dim3((NAA + 255) / 256, BB), 256, 0, stream>>>(
        pd_scores, pd_bboxes, anc, gt_labels, gt_bboxes, mask_gt,
        rcount, done, w, val, rV, rI, pos);
    const int nblk = NBA / 256;   // 525, exact
    k3_out<<<nblk, 256, 0, stream>>>(gt_labels, gt_bboxes, w, val, pos,
                                     o_lab, o_box, o_sc, o_fg, o_ti);
}

// Round 16
// 43.866 us; speedup vs baseline: 2.3144x; 2.3144x over previous
//
#include <hip/hip_runtime.h>
#include <math.h>

#define NCC 80
#define TOPKK 13
#define BB 16
#define NAA 8400
#define NMX 64
#define NROW (BB * NMX)        // 1024
#define NBA  (BB * NAA)        // 134400
#define RCAP 256               // per-row positive capacity (E[n_pos]~4)
#define RPAD 16                // rcount: one counter per 64B line
#define PSTR 14                // kb slow-path LDS stride (13 + sentinel)
#define JZ 4                   // j-loop split across blockIdx.z
#define JPB (NMX / JZ)         // 16 gt rows per z-slice
#define SENT 0x7fffffff
#define EPSF 1e-9f
#define IOUEPS 1e-7f
#define INV_PI2 0.4052847345693511f

__device__ __forceinline__ float ciou_pos(float gx1, float gy1, float gx2, float gy2,
                                          float gw, float gh, float gat, float inter,
                                          float px1, float py1, float px2, float py2)
{
    float w2 = px2 - px1, h2 = py2 - py1;
    float uni = gw * gh + w2 * h2 - inter + IOUEPS;
    float iou = inter / uni;
    float cw = fmaxf(gx2, px2) - fminf(gx1, px1);
    float ch = fmaxf(gy2, py2) - fminf(gy1, py1);
    float c2 = cw * cw + ch * ch + IOUEPS;
    float dx = px1 + px2 - gx1 - gx2;
    float dy = py1 + py2 - gy1 - gy2;
    float rho2 = (dx * dx + dy * dy) * 0.25f;
    float da = atanf(w2 / h2) - gat;
    float v = INV_PI2 * da * da;
    float alpha = v / (v - iou + (1.f + IOUEPS));
    return iou - (rho2 / c2 + v * alpha);
}

__device__ __forceinline__ float ciou2(float gx1, float gy1, float gx2, float gy2,
                                       float gw, float gh, float gat,
                                       float px1, float py1, float px2, float py2,
                                       float pat)
{
    float w2 = px2 - px1, h2 = py2 - py1;
    float iw = fmaxf(fminf(gx2, px2) - fmaxf(gx1, px1), 0.f);
    float ih = fmaxf(fminf(gy2, py2) - fmaxf(gy1, py1), 0.f);
    float inter = iw * ih;
    float uni = gw * gh + w2 * h2 - inter + IOUEPS;
    float iou = inter / uni;
    float cw = fmaxf(gx2, px2) - fminf(gx1, px1);
    float ch = fmaxf(gy2, py2) - fminf(gy1, py1);
    float c2 = cw * cw + ch * ch + IOUEPS;
    float dx = px1 + px2 - gx1 - gx2;
    float dy = py1 + py2 - gy1 - gy2;
    float rho2 = (dx * dx + dy * dy) * 0.25f;
    float da = pat - gat;
    float v = INV_PI2 * da * da;
    float alpha = v / (v - iou + (1.f + IOUEPS));
    return iou - (rho2 / c2 + v * alpha);
}

// KZ: zero padded rcount (the one array KP atomically increments).
__global__ __launch_bounds__(256) void kz_zero(int* __restrict__ rcount)
{
    int i = blockIdx.x * 256 + threadIdx.x;
    if (i < NROW * RPAD) rcount[i] = 0;
}

// KP: anchor-major positivity scan, z-split 4x for TLP (R7-proven fix).
// Grid (33, B, JZ): each block tests 256 anchors against 16 LDS gt rows.
// Positives (al>0, ~6/row) compute CIoU+score and append (val,idx) to
// per-row lists (ballot-aggregated, line-padded counters). jz==0 slice
// zeroes cnt and pos inline.
__global__ __launch_bounds__(256) void kp_scan(
    const float* __restrict__ pd_scores,
    const float* __restrict__ pd_bboxes,
    const float* __restrict__ anc,
    const int*   __restrict__ gt_labels,
    const float* __restrict__ gt_bboxes,
    const float* __restrict__ mask_gt,
    int* __restrict__ cnt, int* __restrict__ pos,
    int* __restrict__ rcount, float* __restrict__ rV, int* __restrict__ rI)
{
    const int tid = threadIdx.x;
    const int lane = tid & 63;
    const int b = blockIdx.y;
    const int jz = blockIdx.z;
    const int a = blockIdx.x * 256 + tid;
    const bool valid = a < NAA;

    __shared__ float4 glds[JPB];
    __shared__ float  mlds[JPB];
    __shared__ float  galds[JPB];
    __shared__ int    gllds[JPB];
    if (tid < JPB) {
        const int row = b * NMX + jz * JPB + tid;
        float4 gg = reinterpret_cast<const float4*>(gt_bboxes)[row];
        glds[tid] = gg;
        mlds[tid] = mask_gt[row];
        galds[tid] = atanf((gg.z - gg.x) / (gg.w - gg.y));
        gllds[tid] = gt_labels[row];
    }
    if (jz == 0 && b == 0 && blockIdx.x < 8) pos[blockIdx.x * 256 + tid] = 0;
    __syncthreads();

    float2 ap = valid ? reinterpret_cast<const float2*>(anc)[a]
                      : make_float2(-1e9f, -1e9f);
    float4 p  = valid ? reinterpret_cast<const float4*>(pd_bboxes)[(size_t)b * NAA + a]
                      : make_float4(0.f, 0.f, 0.f, 0.f);
    if (jz == 0 && valid) cnt[b * NAA + a] = 0;
    const float* scb = pd_scores + ((size_t)b * NAA + a) * NCC;

    for (int jj = 0; jj < JPB; ++jj) {
        float4 g = glds[jj];
        float din = fminf(fminf(ap.x - g.x, ap.y - g.y), fminf(g.z - ap.x, g.w - ap.y));
        bool cand = false;
        float al = 0.f;
        if (din > EPSF && mlds[jj] > 0.f) {
            float iw = fminf(g.z, p.z) - fmaxf(g.x, p.x);
            float ih = fminf(g.w, p.w) - fmaxf(g.y, p.y);
            if (iw > 0.f && ih > 0.f) {
                float c = ciou_pos(g.x, g.y, g.z, g.w, g.z - g.x, g.w - g.y,
                                   galds[jj], iw * ih, p.x, p.y, p.z, p.w);
                float o = fmaxf(c, 0.f);
                float o2 = o * o;
                al = scb[gllds[jj]] * (o2 * o2 * o2);
                cand = al > 0.f;
            }
        }
        unsigned long long m = __ballot(cand);
        if (m) {
            const int row = b * NMX + jz * JPB + jj;
            int base = 0;
            int wc = __popcll(m);
            if (lane == 0) base = atomicAdd(&rcount[row * RPAD], wc);
            base = __shfl(base, 0, 64);
            if (cand) {
                int pp = base + __popcll(m & ((1ull << lane) - 1ull));
                if (pp < RCAP) {
                    rV[(size_t)row * RCAP + pp] = al;
                    rI[(size_t)row * RCAP + pp] = a;
                }
            }
        }
    }
}

// KB: per-row finalize, one wave per row (4 rows/block). Unchanged from R14.
__global__ __launch_bounds__(256) void kb_fin(
    const float* __restrict__ anc,
    const float* __restrict__ gt_bboxes,
    const float* __restrict__ mask_gt,
    const int* __restrict__ rcount,
    const float* __restrict__ rV, const int* __restrict__ rI,
    int* __restrict__ cnt)
{
    const int tid = threadIdx.x;
    const int lane = tid & 63, wid = tid >> 6;
    const int row = blockIdx.x * 4 + wid;
    const bool active = row < NROW && mask_gt[row] > 0.f;

    __shared__ float Lv[256 * PSTR];
    __shared__ int   Li[256 * PSTR];

    if (active) {
        const int b = row >> 6, j = row & 63;
        int n = rcount[row * RPAD]; if (n > RCAP) n = RCAP;

        if (n <= TOPKK) {
            unsigned int pm = 0;
            if (lane < n) {
                int a = rI[(size_t)row * RCAP + lane];
                atomicAdd(&cnt[(size_t)b * NAA + a], 1 + (j << 8));
                if (a < TOPKK) pm = 1u << a;
            }
#pragma unroll
            for (int s = 1; s < 64; s <<= 1) pm |= __shfl_xor(pm, s, 64);
            if (lane < TOPKK) {
                unsigned int bits = (~pm) & 0x1fffu;
                if ((bits >> lane) & 1u) {
                    int rank = __popc(bits & ((1u << lane) - 1u));
                    if (rank < TOPKK - n) {
                        float4 g = reinterpret_cast<const float4*>(gt_bboxes)[row];
                        float2 ap = reinterpret_cast<const float2*>(anc)[lane];
                        float din = fminf(fminf(ap.x - g.x, ap.y - g.y),
                                          fminf(g.z - ap.x, g.w - ap.y));
                        if (din > EPSF)
                            atomicAdd(&cnt[(size_t)b * NAA + lane], 1 + (j << 8));
                    }
                }
            }
        } else {
            // slow path: exact top-13 of the positive list
            float lv[TOPKK]; int li[TOPKK];
#pragma unroll
            for (int k = 0; k < TOPKK; ++k) { lv[k] = -1.f; li[k] = SENT; }
            for (int t = lane; t < n; t += 64) {
                float al = rV[(size_t)row * RCAP + t];
                int a = rI[(size_t)row * RCAP + t];
                if (al > lv[TOPKK - 1] || (al == lv[TOPKK - 1] && a < li[TOPKK - 1])) {
                    lv[TOPKK - 1] = al; li[TOPKK - 1] = a;
#pragma unroll
                    for (int k = TOPKK - 1; k > 0; --k) {
                        if (lv[k] > lv[k - 1] || (lv[k] == lv[k - 1] && li[k] < li[k - 1])) {
                            float tv = lv[k]; lv[k] = lv[k - 1]; lv[k - 1] = tv;
                            int ti = li[k]; li[k] = li[k - 1]; li[k - 1] = ti;
                        } else break;
                    }
                }
            }
#pragma unroll
            for (int k = 0; k < TOPKK; ++k) { Lv[tid * PSTR + k] = lv[k]; Li[tid * PSTR + k] = li[k]; }
            Lv[tid * PSTR + TOPKK] = -1.f;     // sentinel
            Li[tid * PSTR + TOPKK] = SENT;

            int p = 0;
            int myi = SENT;
            for (int r = 0; r < TOPKK; ++r) {
                float hv = Lv[tid * PSTR + p];
                int   hi = Li[tid * PSTR + p];
                float wv = hv; int wi = hi;
#pragma unroll
                for (int s = 1; s < 64; s <<= 1) {
                    float ov = __shfl_xor(wv, s, 64);
                    int   oi = __shfl_xor(wi, s, 64);
                    if (ov > wv || (ov == wv && oi < wi)) { wv = ov; wi = oi; }
                }
                if (lane == r) myi = wi;
                if (hi == wi && wi != SENT) ++p;
            }
            if (lane < TOPKK && myi != SENT)
                atomicAdd(&cnt[(size_t)b * NAA + myi], 1 + (j << 8));
        }
    }
}

// K2: per-anchor multi-gt resolution + per-row pos maxima (unchanged).
__global__ __launch_bounds__(256) void k2_resolve(
    const float* __restrict__ pd_scores,
    const float* __restrict__ pd_bboxes,
    const float* __restrict__ anc,
    const int*   __restrict__ gt_labels,
    const float* __restrict__ gt_bboxes,
    const float* __restrict__ mask_gt,
    const int* __restrict__ cnt,
    int* __restrict__ tgt, int* __restrict__ fgm, float* __restrict__ alv,
    int* __restrict__ pos)
{
    const int tid = threadIdx.x;
    const int b = blockIdx.y;
    const int a = blockIdx.x * 256 + tid;

    __shared__ float4 glds[NMX];
    __shared__ float  mlds[NMX];
    __shared__ float  galds[NMX];
    if (tid < NMX) {
        float4 gg = reinterpret_cast<const float4*>(gt_bboxes)[b * NMX + tid];
        glds[tid] = gg;
        mlds[tid] = mask_gt[b * NMX + tid];
        galds[tid] = atanf((gg.z - gg.x) / (gg.w - gg.y));
    }
    __syncthreads();
    if (a >= NAA) return;

    const int id = b * NAA + a;
    const int v = cnt[id];
    const int fg = v & 0xff;
    int tj = 0, f = 0;
    float al = 0.f;
    if (fg > 0) {
        f = 1;
        float2 ap = reinterpret_cast<const float2*>(anc)[a];
        float4 p = reinterpret_cast<const float4*>(pd_bboxes)[id];
        float pat = atanf((p.z - p.x) / (p.w - p.y));
        if (fg == 1) {
            tj = v >> 8;
        } else {
            float bv = -1.f; int bj = 0;
            for (int jj = 0; jj < NMX; ++jj) {
                float4 g = glds[jj];
                float din = fminf(fminf(ap.x - g.x, ap.y - g.y), fminf(g.z - ap.x, g.w - ap.y));
                float ov = 0.f;
                if (din > EPSF && mlds[jj] > 0.f) {
                    float c = ciou2(g.x, g.y, g.z, g.w, g.z - g.x, g.w - g.y, galds[jj],
                                    p.x, p.y, p.z, p.w, pat);
                    ov = fmaxf(c, 0.f);
                }
                if (ov > bv) { bv = ov; bj = jj; }   // strict > == first-argmax
            }
            tj = bj;
        }
        float4 g = glds[tj];
        float din = fminf(fminf(ap.x - g.x, ap.y - g.y), fminf(g.z - ap.x, g.w - ap.y));
        if (din > EPSF && mlds[tj] > 0.f) {
            float c = ciou2(g.x, g.y, g.z, g.w, g.z - g.x, g.w - g.y, galds[tj],
                            p.x, p.y, p.z, p.w, pat);
            float ov = fmaxf(c, 0.f);
            int gl = gt_labels[b * NMX + tj];
            float s = pd_scores[(size_t)id * NCC + gl];
            float o2 = ov * ov;
            al = s * (o2 * o2 * o2);
            if (ov > 0.f)
                atomicMax((unsigned int*)&pos[NROW + b * NMX + tj], __float_as_uint(ov));
        }
        if (al > 0.f)
            atomicMax((unsigned int*)&pos[b * NMX + tj], __float_as_uint(al));
    }
    tgt[id] = tj; fgm[id] = f; alv[id] = al;
}

// K3: all outputs, fully written (unchanged).
__global__ __launch_bounds__(256) void k3_out(
    const int* __restrict__ gt_labels,
    const float* __restrict__ gt_bboxes,
    const int* __restrict__ tgt, const int* __restrict__ fgm,
    const float* __restrict__ alv, const int* __restrict__ pos,
    float* __restrict__ o_lab, float* __restrict__ o_box, float* __restrict__ o_sc,
    float* __restrict__ o_fg, float* __restrict__ o_ti)
{
    const int id0 = blockIdx.x * 256;
    const int tid = threadIdx.x;
    const int id = id0 + tid;
    const int b = id / NAA;
    const int tj = tgt[id];
    const int f = fgm[id];
    int lab = gt_labels[b * NMX + tj]; lab = lab < 0 ? 0 : lab;
    float4 gb = reinterpret_cast<const float4*>(gt_bboxes)[b * NMX + tj];
    o_lab[id] = (float)lab;
    reinterpret_cast<float4*>(o_box)[id] = gb;
    o_fg[id] = f ? 1.f : 0.f;
    o_ti[id] = (float)tj;
    float val = 0.f;
    if (f) {
        float pa = __uint_as_float((unsigned int)pos[b * NMX + tj]);
        float po = __uint_as_float((unsigned int)pos[NROW + b * NMX + tj]);
        val = (alv[id] * po) / (pa + EPSF);
    }
    __shared__ int   s_lab[256];
    __shared__ float s_val[256];
    s_lab[tid] = lab;
    s_val[tid] = val;
    __syncthreads();
    float4* dst = reinterpret_cast<float4*>(o_sc + (size_t)id0 * NCC);
    const int NV = 256 * NCC / 4;   // 5120 float4s per block
#pragma unroll 4
    for (int i = tid; i < NV; i += 256) {
        int aa = i / (NCC / 4);
        int c0 = (i - aa * (NCC / 4)) * 4;
        int la = s_lab[aa];
        float vv = s_val[aa];
        float4 w;
        w.x = (la == c0 + 0) ? vv : 0.f;
        w.y = (la == c0 + 1) ? vv : 0.f;
        w.z = (la == c0 + 2) ? vv : 0.f;
        w.w = (la == c0 + 3) ? vv : 0.f;
        dst[i] = w;
    }
}

extern "C" void kernel_launch(void* const* d_in, const int* in_sizes, int n_in,
                              void* d_out, int out_size, void* d_ws, size_t ws_size,
                              hipStream_t stream)
{
    const float* pd_scores = (const float*)d_in[0];
    const float* pd_bboxes = (const float*)d_in[1];
    const float* anc       = (const float*)d_in[2];
    // d_in[3] rfields: unused by the reference
    const int*   gt_labels = (const int*)d_in[4];
    const float* gt_bboxes = (const float*)d_in[5];
    const float* mask_gt   = (const float*)d_in[6];

    const size_t nba = (size_t)NBA;
    int* cnt    = (int*)d_ws;                       // NBA
    int* pos    = cnt + nba;                        // 2*NROW
    int* rcount = pos + 2 * NROW;                   // NROW*RPAD
    float* rV   = (float*)(rcount + NROW * RPAD);   // NROW*RCAP
    int* rI     = (int*)(rV + (size_t)NROW * RCAP); // NROW*RCAP
    int* tgt    = rI + (size_t)NROW * RCAP;         // NBA
    int* fgm    = tgt + nba;                        // NBA
    float* alv  = (float*)(fgm + nba);              // NBA

    float* out = (float*)d_out;
    float* o_lab = out;                 // (B,NA)
    float* o_box = out + nba;           // (B,NA,4)
    float* o_sc  = out + nba * 5;       // (B,NA,NC)
    float* o_fg  = out + nba * 85;      // (B,NA)
    float* o_ti  = out + nba * 86;      // (B,NA)

    kz_zero<<<(NROW * RPAD + 255) / 256, 256, 0, stream>>>(rcount);
    kp_scan<<<dim3((NAA + 255) / 256, BB, JZ), 256, 0, stream>>>(
        pd_scores, pd_bboxes, anc, gt_labels, gt_bboxes, mask_gt,
        cnt, pos, rcount, rV, rI);
    kb_fin<<<NROW / 4, 256, 0, stream>>>(anc, gt_bboxes, mask_gt,
                                         rcount, rV, rI, cnt);
    k2_resolve<<<dim3((NAA + 255) / 256, BB), 256, 0, stream>>>(
        pd_scores, pd_bboxes, anc, gt_labels, gt_bboxes, mask_gt, cnt,
        tgt, fgm, alv, pos);
    const int nblk = NBA / 256;   // 525, exact
    k3_out<<<nblk, 256, 0, stream>>>(gt_labels, gt_bboxes, tgt, fgm, alv, pos,
                                     o_lab, o_box, o_sc, o_fg, o_ti);
}

// Round 17
// 38.721 us; speedup vs baseline: 2.6219x; 1.1329x over previous
//
#include <hip/hip_runtime.h>
#include <math.h>

#define NCC 80
#define TOPKK 13
#define BB 16
#define NAA 8400
#define NMX 64
#define NROW (BB * NMX)        // 1024
#define NBA  (BB * NAA)        // 134400
#define NBK 33                 // kp x-blocks (ceil(8400/256))
#define NWRD (NBK * 4)         // 132 u64 ballot words per row
#define JZ 4                   // j-loop split across blockIdx.z
#define JPB (NMX / JZ)         // 16 gt rows per z-slice
#define SENT 0x7fffffff
#define EPSF 1e-9f
#define IOUEPS 1e-7f
#define INV_PI2 0.4052847345693511f

typedef unsigned long long u64;

__device__ __forceinline__ float ciou_pos(float gx1, float gy1, float gx2, float gy2,
                                          float gw, float gh, float gat, float inter,
                                          float px1, float py1, float px2, float py2)
{
    float w2 = px2 - px1, h2 = py2 - py1;
    float uni = gw * gh + w2 * h2 - inter + IOUEPS;
    float iou = inter / uni;
    float cw = fmaxf(gx2, px2) - fminf(gx1, px1);
    float ch = fmaxf(gy2, py2) - fminf(gy1, py1);
    float c2 = cw * cw + ch * ch + IOUEPS;
    float dx = px1 + px2 - gx1 - gx2;
    float dy = py1 + py2 - gy1 - gy2;
    float rho2 = (dx * dx + dy * dy) * 0.25f;
    float da = atanf(w2 / h2) - gat;
    float v = INV_PI2 * da * da;
    float alpha = v / (v - iou + (1.f + IOUEPS));
    return iou - (rho2 / c2 + v * alpha);
}

__device__ __forceinline__ float ciou2(float gx1, float gy1, float gx2, float gy2,
                                       float gw, float gh, float gat,
                                       float px1, float py1, float px2, float py2,
                                       float pat)
{
    float w2 = px2 - px1, h2 = py2 - py1;
    float iw = fmaxf(fminf(gx2, px2) - fmaxf(gx1, px1), 0.f);
    float ih = fmaxf(fminf(gy2, py2) - fmaxf(gy1, py1), 0.f);
    float inter = iw * ih;
    float uni = gw * gh + w2 * h2 - inter + IOUEPS;
    float iou = inter / uni;
    float cw = fmaxf(gx2, px2) - fminf(gx1, px1);
    float ch = fmaxf(gy2, py2) - fminf(gy1, py1);
    float c2 = cw * cw + ch * ch + IOUEPS;
    float dx = px1 + px2 - gx1 - gx2;
    float dy = py1 + py2 - gy1 - gy2;
    float rho2 = (dx * dx + dy * dy) * 0.25f;
    float da = pat - gat;
    float v = INV_PI2 * da * da;
    float alpha = v / (v - iou + (1.f + IOUEPS));
    return iou - (rho2 / c2 + v * alpha);
}

// KP: anchor-major positivity scan, z-split 4x. Per (row, x-block, wave):
// ONE unconditional u64 ballot store (no atomics, no zeroed counters -> kz
// eliminated). jz==0 slice zeroes cnt and pos inline. Positivity = in-gt
// AND masked AND pred-overlap AND align>0 (needs full CIoU sign + score).
__global__ __launch_bounds__(256) void kp_scan(
    const float* __restrict__ pd_scores,
    const float* __restrict__ pd_bboxes,
    const float* __restrict__ anc,
    const int*   __restrict__ gt_labels,
    const float* __restrict__ gt_bboxes,
    const float* __restrict__ mask_gt,
    int* __restrict__ cnt, int* __restrict__ pos,
    u64* __restrict__ bmask)
{
    const int tid = threadIdx.x;
    const int lane = tid & 63, wid = tid >> 6;
    const int b = blockIdx.y;
    const int jz = blockIdx.z;
    const int xb = blockIdx.x;
    const int a = xb * 256 + tid;
    const bool valid = a < NAA;

    __shared__ float4 glds[JPB];
    __shared__ float  mlds[JPB];
    __shared__ float  galds[JPB];
    __shared__ int    gllds[JPB];
    if (tid < JPB) {
        const int row = b * NMX + jz * JPB + tid;
        float4 gg = reinterpret_cast<const float4*>(gt_bboxes)[row];
        glds[tid] = gg;
        mlds[tid] = mask_gt[row];
        galds[tid] = atanf((gg.z - gg.x) / (gg.w - gg.y));
        gllds[tid] = gt_labels[row];
    }
    if (jz == 0 && b == 0 && xb < 8) pos[xb * 256 + tid] = 0;
    __syncthreads();

    float2 ap = valid ? reinterpret_cast<const float2*>(anc)[a]
                      : make_float2(-1e9f, -1e9f);
    float4 p  = valid ? reinterpret_cast<const float4*>(pd_bboxes)[(size_t)b * NAA + a]
                      : make_float4(0.f, 0.f, 0.f, 0.f);
    if (jz == 0 && valid) cnt[b * NAA + a] = 0;
    const float* scb = pd_scores + ((size_t)b * NAA + a) * NCC;

    for (int jj = 0; jj < JPB; ++jj) {
        float4 g = glds[jj];
        float din = fminf(fminf(ap.x - g.x, ap.y - g.y), fminf(g.z - ap.x, g.w - ap.y));
        bool cand = false;
        if (din > EPSF && mlds[jj] > 0.f) {
            float iw = fminf(g.z, p.z) - fmaxf(g.x, p.x);
            float ih = fminf(g.w, p.w) - fmaxf(g.y, p.y);
            if (iw > 0.f && ih > 0.f) {
                float c = ciou_pos(g.x, g.y, g.z, g.w, g.z - g.x, g.w - g.y,
                                   galds[jj], iw * ih, p.x, p.y, p.z, p.w);
                float o = fmaxf(c, 0.f);
                float o2 = o * o;
                float al = scb[gllds[jj]] * (o2 * o2 * o2);
                cand = al > 0.f;
            }
        }
        u64 m = __ballot(cand);
        if (lane == 0) {
            const int row = b * NMX + jz * JPB + jj;
            bmask[(size_t)row * NWRD + xb * 4 + wid] = m;   // unconditional
        }
    }
}

// KB: per-row finalize from ballot words, one wave per row, NO LDS, no
// block syncs. n<=13: enumerate set bits -> scatter (values never needed)
// + ranked din-filtered fillers from {0..12}. n>13 (rare): recompute al for
// each positive, depth-13 register lists, 13-round select-chain tournament,
// exact (val desc, idx asc).
__global__ __launch_bounds__(256) void kb_fin(
    const float* __restrict__ pd_scores,
    const float* __restrict__ pd_bboxes,
    const float* __restrict__ anc,
    const int*   __restrict__ gt_labels,
    const float* __restrict__ gt_bboxes,
    const float* __restrict__ mask_gt,
    const u64* __restrict__ bmask,
    int* __restrict__ cnt)
{
    const int tid = threadIdx.x;
    const int lane = tid & 63, wid = tid >> 6;
    const int row = blockIdx.x * 4 + wid;
    if (row >= NROW || mask_gt[row] <= 0.f) return;   // wave-uniform exit
    const int b = row >> 6, j = row & 63;

    const u64* bm = bmask + (size_t)row * NWRD;
    u64 w0 = bm[lane];
    u64 w1 = bm[lane + 64];
    u64 w2 = (lane < NWRD - 128) ? bm[lane + 128] : 0ull;

    int n = __popcll(w0) + __popcll(w1) + __popcll(w2);
#pragma unroll
    for (int s = 1; s < 64; s <<= 1) n += __shfl_xor(n, s, 64);

    unsigned int pmv = (lane == 0) ? (unsigned int)(w0 & 0x1fffull) : 0u;
    pmv = __shfl(pmv, 0, 64);

    const int cb = (int)((size_t)b * NAA);

    if (n <= TOPKK) {
        // ---- fast path: every positive wins; indices only ----
        {
            u64 w = w0; int base = (lane >> 2) * 256 + (lane & 3) * 64;
            while (w) { int t = __ffsll(w) - 1; w &= w - 1;
                atomicAdd(&cnt[cb + base + t], 1 + (j << 8)); }
        }
        {
            int W = lane + 64;
            u64 w = w1; int base = (W >> 2) * 256 + (W & 3) * 64;
            while (w) { int t = __ffsll(w) - 1; w &= w - 1;
                atomicAdd(&cnt[cb + base + t], 1 + (j << 8)); }
        }
        if (lane < NWRD - 128) {
            int W = lane + 128;
            u64 w = w2; int base = (W >> 2) * 256 + (W & 3) * 64;
            while (w) { int t = __ffsll(w) - 1; w &= w - 1;
                atomicAdd(&cnt[cb + base + t], 1 + (j << 8)); }
        }
        // fillers: (13-n) smallest non-positive indices, all in {0..12}
        if (lane < TOPKK) {
            unsigned int bits = (~pmv) & 0x1fffu;
            if ((bits >> lane) & 1u) {
                int rank = __popc(bits & ((1u << lane) - 1u));
                if (rank < TOPKK - n) {
                    float4 g = reinterpret_cast<const float4*>(gt_bboxes)[row];
                    float2 ap = reinterpret_cast<const float2*>(anc)[lane];
                    float din = fminf(fminf(ap.x - g.x, ap.y - g.y),
                                      fminf(g.z - ap.x, g.w - ap.y));
                    if (din > EPSF)
                        atomicAdd(&cnt[cb + lane], 1 + (j << 8));
                }
            }
        }
        return;
    }

    // ---- slow path (rare): recompute al for positives, exact top-13 ----
    const float4 g = reinterpret_cast<const float4*>(gt_bboxes)[row];
    const float gw = g.z - g.x, gh = g.w - g.y;
    const float gat = atanf(gw / gh);
    const int gl = gt_labels[row];
    const float* sc = pd_scores + (size_t)b * NAA * NCC + gl;
    const float4* pb = reinterpret_cast<const float4*>(pd_bboxes) + (size_t)b * NAA;

    float lv[TOPKK]; int li[TOPKK];
#pragma unroll
    for (int k = 0; k < TOPKK; ++k) { lv[k] = -1.f; li[k] = SENT; }

#define INSERT(AL, A)                                                            \
    if ((AL) > lv[TOPKK - 1] || ((AL) == lv[TOPKK - 1] && (A) < li[TOPKK - 1])) { \
        lv[TOPKK - 1] = (AL); li[TOPKK - 1] = (A);                               \
        _Pragma("unroll")                                                        \
        for (int k = TOPKK - 1; k > 0; --k) {                                    \
            if (lv[k] > lv[k - 1] || (lv[k] == lv[k - 1] && li[k] < li[k - 1])) {\
                float tv = lv[k]; lv[k] = lv[k - 1]; lv[k - 1] = tv;             \
                int ti = li[k]; li[k] = li[k - 1]; li[k - 1] = ti;               \
            } else break;                                                        \
        }                                                                        \
    }

#define PROCW(WRD, WIDX)                                                         \
    {                                                                            \
        u64 w = (WRD); int base = ((WIDX) >> 2) * 256 + ((WIDX) & 3) * 64;       \
        while (w) {                                                              \
            int t = __ffsll(w) - 1; w &= w - 1;                                  \
            int a = base + t;                                                    \
            float4 p = pb[a];                                                    \
            float iw = fminf(g.z, p.z) - fmaxf(g.x, p.x);                        \
            float ih = fminf(g.w, p.w) - fmaxf(g.y, p.y);                        \
            float c = ciou_pos(g.x, g.y, g.z, g.w, gw, gh, gat, iw * ih,         \
                               p.x, p.y, p.z, p.w);                              \
            float o = fmaxf(c, 0.f);                                             \
            float o2 = o * o;                                                    \
            float al = sc[(size_t)a * NCC] * (o2 * o2 * o2);                     \
            INSERT(al, a);                                                       \
        }                                                                        \
    }

    PROCW(w0, lane);
    PROCW(w1, lane + 64);
    if (lane < NWRD - 128) PROCW(w2, lane + 128);
#undef PROCW
#undef INSERT

    int pp = 0;
    int myi = SENT;
    for (int rnd = 0; rnd < TOPKK; ++rnd) {
        float hv = -1.f; int hi = SENT;
#pragma unroll
        for (int k = 0; k < TOPKK; ++k) if (pp == k) { hv = lv[k]; hi = li[k]; }
        float wv = hv; int wi = hi;
#pragma unroll
        for (int s = 1; s < 64; s <<= 1) {
            float ov = __shfl_xor(wv, s, 64);
            int   oi = __shfl_xor(wi, s, 64);
            if (ov > wv || (ov == wv && oi < wi)) { wv = ov; wi = oi; }
        }
        if (lane == rnd) myi = wi;
        if (hi == wi && wi != SENT) ++pp;
    }
    if (lane < TOPKK && myi != SENT)
        atomicAdd(&cnt[cb + myi], 1 + (j << 8));
}

// K2: per-anchor multi-gt resolution + per-row pos maxima (unchanged).
__global__ __launch_bounds__(256) void k2_resolve(
    const float* __restrict__ pd_scores,
    const float* __restrict__ pd_bboxes,
    const float* __restrict__ anc,
    const int*   __restrict__ gt_labels,
    const float* __restrict__ gt_bboxes,
    const float* __restrict__ mask_gt,
    const int* __restrict__ cnt,
    int* __restrict__ tgt, int* __restrict__ fgm, float* __restrict__ alv,
    int* __restrict__ pos)
{
    const int tid = threadIdx.x;
    const int b = blockIdx.y;
    const int a = blockIdx.x * 256 + tid;

    __shared__ float4 glds[NMX];
    __shared__ float  mlds[NMX];
    __shared__ float  galds[NMX];
    if (tid < NMX) {
        float4 gg = reinterpret_cast<const float4*>(gt_bboxes)[b * NMX + tid];
        glds[tid] = gg;
        mlds[tid] = mask_gt[b * NMX + tid];
        galds[tid] = atanf((gg.z - gg.x) / (gg.w - gg.y));
    }
    __syncthreads();
    if (a >= NAA) return;

    const int id = b * NAA + a;
    const int v = cnt[id];
    const int fg = v & 0xff;
    int tj = 0, f = 0;
    float al = 0.f;
    if (fg > 0) {
        f = 1;
        float2 ap = reinterpret_cast<const float2*>(anc)[a];
        float4 p = reinterpret_cast<const float4*>(pd_bboxes)[id];
        float pat = atanf((p.z - p.x) / (p.w - p.y));
        if (fg == 1) {
            tj = v >> 8;
        } else {
            float bv = -1.f; int bj = 0;
            for (int jj = 0; jj < NMX; ++jj) {
                float4 g = glds[jj];
                float din = fminf(fminf(ap.x - g.x, ap.y - g.y), fminf(g.z - ap.x, g.w - ap.y));
                float ov = 0.f;
                if (din > EPSF && mlds[jj] > 0.f) {
                    float c = ciou2(g.x, g.y, g.z, g.w, g.z - g.x, g.w - g.y, galds[jj],
                                    p.x, p.y, p.z, p.w, pat);
                    ov = fmaxf(c, 0.f);
                }
                if (ov > bv) { bv = ov; bj = jj; }   // strict > == first-argmax
            }
            tj = bj;
        }
        float4 g = glds[tj];
        float din = fminf(fminf(ap.x - g.x, ap.y - g.y), fminf(g.z - ap.x, g.w - ap.y));
        if (din > EPSF && mlds[tj] > 0.f) {
            float c = ciou2(g.x, g.y, g.z, g.w, g.z - g.x, g.w - g.y, galds[tj],
                            p.x, p.y, p.z, p.w, pat);
            float ov = fmaxf(c, 0.f);
            int gl = gt_labels[b * NMX + tj];
            float s = pd_scores[(size_t)id * NCC + gl];
            float o2 = ov * ov;
            al = s * (o2 * o2 * o2);
            if (ov > 0.f)
                atomicMax((unsigned int*)&pos[NROW + b * NMX + tj], __float_as_uint(ov));
        }
        if (al > 0.f)
            atomicMax((unsigned int*)&pos[b * NMX + tj], __float_as_uint(al));
    }
    tgt[id] = tj; fgm[id] = f; alv[id] = al;
}

// K3: all outputs, fully written (unchanged).
__global__ __launch_bounds__(256) void k3_out(
    const int* __restrict__ gt_labels,
    const float* __restrict__ gt_bboxes,
    const int* __restrict__ tgt, const int* __restrict__ fgm,
    const float* __restrict__ alv, const int* __restrict__ pos,
    float* __restrict__ o_lab, float* __restrict__ o_box, float* __restrict__ o_sc,
    float* __restrict__ o_fg, float* __restrict__ o_ti)
{
    const int id0 = blockIdx.x * 256;
    const int tid = threadIdx.x;
    const int id = id0 + tid;
    const int b = id / NAA;
    const int tj = tgt[id];
    const int f = fgm[id];
    int lab = gt_labels[b * NMX + tj]; lab = lab < 0 ? 0 : lab;
    float4 gb = reinterpret_cast<const float4*>(gt_bboxes)[b * NMX + tj];
    o_lab[id] = (float)lab;
    reinterpret_cast<float4*>(o_box)[id] = gb;
    o_fg[id] = f ? 1.f : 0.f;
    o_ti[id] = (float)tj;
    float val = 0.f;
    if (f) {
        float pa = __uint_as_float((unsigned int)pos[b * NMX + tj]);
        float po = __uint_as_float((unsigned int)pos[NROW + b * NMX + tj]);
        val = (alv[id] * po) / (pa + EPSF);
    }
    __shared__ int   s_lab[256];
    __shared__ float s_val[256];
    s_lab[tid] = lab;
    s_val[tid] = val;
    __syncthreads();
    float4* dst = reinterpret_cast<float4*>(o_sc + (size_t)id0 * NCC);
    const int NV = 256 * NCC / 4;   // 5120 float4s per block
#pragma unroll 4
    for (int i = tid; i < NV; i += 256) {
        int aa = i / (NCC / 4);
        int c0 = (i - aa * (NCC / 4)) * 4;
        int la = s_lab[aa];
        float vv = s_val[aa];
        float4 w;
        w.x = (la == c0 + 0) ? vv : 0.f;
        w.y = (la == c0 + 1) ? vv : 0.f;
        w.z = (la == c0 + 2) ? vv : 0.f;
        w.w = (la == c0 + 3) ? vv : 0.f;
        dst[i] = w;
    }
}

extern "C" void kernel_launch(void* const* d_in, const int* in_sizes, int n_in,
                              void* d_out, int out_size, void* d_ws, size_t ws_size,
                              hipStream_t stream)
{
    const float* pd_scores = (const float*)d_in[0];
    const float* pd_bboxes = (const float*)d_in[1];
    const float* anc       = (const float*)d_in[2];
    // d_in[3] rfields: unused by the reference
    const int*   gt_labels = (const int*)d_in[4];
    const float* gt_bboxes = (const float*)d_in[5];
    const float* mask_gt   = (const float*)d_in[6];

    const size_t nba = (size_t)NBA;
    int* cnt    = (int*)d_ws;                       // NBA
    int* pos    = cnt + nba;                        // 2*NROW
    u64* bmask  = (u64*)(pos + 2 * NROW);           // NROW*NWRD u64 (8B-aligned: 136448*4 bytes off)
    int* tgt    = (int*)(bmask + (size_t)NROW * NWRD);  // NBA
    int* fgm    = tgt + nba;                        // NBA
    float* alv  = (float*)(fgm + nba);              // NBA

    float* out = (float*)d_out;
    float* o_lab = out;                 // (B,NA)
    float* o_box = out + nba;           // (B,NA,4)
    float* o_sc  = out + nba * 5;       // (B,NA,NC)
    float* o_fg  = out + nba * 85;      // (B,NA)
    float* o_ti  = out + nba * 86;      // (B,NA)

    kp_scan<<<dim3(NBK, BB, JZ), 256, 0, stream>>>(
        pd_scores, pd_bboxes, anc, gt_labels, gt_bboxes, mask_gt,
        cnt, pos, bmask);
    kb_fin<<<NROW / 4, 256, 0, stream>>>(pd_scores, pd_bboxes, anc, gt_labels,
                                         gt_bboxes, mask_gt, bmask, cnt);
    k2_resolve<<<dim3(NBK, BB), 256, 0, stream>>>(
        pd_scores, pd_bboxes, anc, gt_labels, gt_bboxes, mask_gt, cnt,
        tgt, fgm, alv, pos);
    const int nblk = NBA / 256;   // 525, exact
    k3_out<<<nblk, 256, 0, stream>>>(gt_labels, gt_bboxes, tgt, fgm, alv, pos,
                                     o_lab, o_box, o_sc, o_fg, o_ti);
}